// Round 3
// baseline (214.323 us; speedup 1.0000x reference)
//
#include <hip/hip_runtime.h>

// MinimalSSM on MFMA (bf16): Bu = U@B^T, diagonal scan (fp32, exact chunked),
// Y = H@C^T + U@D^T.  T=262144, DIN=64, DS=128.
// R3: K1 aggregates in-register (no serial scan, 16 KB LDS); K2 serial over
// 128 segments; K3 parallel weighted lookback for carry, sH overlaid on sBu
// (49.7 KB LDS -> 3 blocks/CU), all LDS maps <=2-way bank conflicts.

#define TT   262144
#define DIN  64
#define DS   128
#define DTC  0.01f
#define L    128
#define NG   (TT / L)        // 2048 chunks
#define SEGL 16              // chunks per segment
#define NSEG (NG / SEGL)     // 128 segments

typedef short  s8v  __attribute__((ext_vector_type(8)));
typedef float  f4v  __attribute__((ext_vector_type(4)));

__device__ __forceinline__ unsigned short f2bf(float f) {
    unsigned u = __float_as_uint(f);
    u += 0x7fffu + ((u >> 16) & 1u);        // round-to-nearest-even
    return (unsigned short)(u >> 16);
}

__device__ __forceinline__ s8v pack8(float4 a, float4 b) {
    union { unsigned short u[8]; s8v v; } r;
    r.u[0] = f2bf(a.x); r.u[1] = f2bf(a.y); r.u[2] = f2bf(a.z); r.u[3] = f2bf(a.w);
    r.u[4] = f2bf(b.x); r.u[5] = f2bf(b.y); r.u[6] = f2bf(b.z); r.u[7] = f2bf(b.w);
    return r.v;
}

// A-frag slot in sA: lane field XOR-swizzled; reads (m varies) and staged
// writes (slot-linear) are both conflict-free.
__device__ __forceinline__ const s8v* afrag(const unsigned short* sA,
                                            int mt, int ks, int q, int m) {
    int slot = (mt * 2 + ks) * 64 + (q << 4) + (m ^ (q << 2) ^ ks);
    return (const s8v*)&sA[slot * 8];
}

// Stage one chunk of U (L x 64 fp32) -> bf16 A-frags, slot-linear per thread:
// LDS writes are lane-consecutive (conflict-free); global reads coalesce to
// 128 B segments per row.
__device__ __forceinline__ void stage_U(const float* __restrict__ Ug,
                                        unsigned short* __restrict__ sA,
                                        int tid) {
    #pragma unroll
    for (int p = 0; p < 2; ++p) {
        int u  = tid + p * 512;                 // u = slot index, 0..1023
        int mt = u >> 7, ks = (u >> 6) & 1, q = (u >> 4) & 3, lo = u & 15;
        int m  = lo ^ (q << 2) ^ ks;
        const float4* gp = (const float4*)(Ug + (mt * 16 + m) * DIN + ks * 32 + q * 8);
        *(s8v*)&sA[u * 8] = pack8(gp[0], gp[1]);
    }
}

// B-operand fragment: lane(q,m) holds M[row][k0..k0+7].
__device__ __forceinline__ s8v load_bfrag(const float* __restrict__ M,
                                          int row, int k0, int ld) {
    const float4* p = (const float4*)(M + row * ld + k0);
    return pack8(p[0], p[1]);
}

// ---------------------------------------------------------------- K1
// agg[g][s] = sum_t a_s^(L-1-t) * Bu[t,s], computed straight from MFMA
// accumulators (C-layout: row t_loc = q*4+r, col s = 16w+m) + q-butterfly.
__global__ __launch_bounds__(512, 8) void ssm_k1(
    const float* __restrict__ U, const float* __restrict__ Alog,
    const float* __restrict__ B, float* __restrict__ agg,
    float* __restrict__ segAgg)
{
    __shared__ __align__(16) unsigned short sA[8192];   // 16 KB
    const int g    = blockIdx.x;
    const int tid  = threadIdx.x;
    const int lane = tid & 63;
    const int w    = tid >> 6;          // wave = 16-state strip
    const int q    = lane >> 4, m = lane & 15;
    const int s    = 16 * w + m;

    stage_U(U + (size_t)g * L * DIN, sA, tid);

    s8v Bf[2];
    #pragma unroll
    for (int ks = 0; ks < 2; ++ks)
        Bf[ks] = load_bfrag(B, s, ks * 32 + q * 8, DIN);

    const float cA   = Alog[s] * DTC;
    const float aInv = __expf(-cA);
    __syncthreads();

    float wsum = 0.f;
    #pragma unroll
    for (int mt = 0; mt < 8; ++mt) {
        f4v acc = (f4v){0.f, 0.f, 0.f, 0.f};
        #pragma unroll
        for (int ks = 0; ks < 2; ++ks)
            acc = __builtin_amdgcn_mfma_f32_16x16x32_bf16(*afrag(sA, mt, ks, q, m), Bf[ks], acc, 0, 0, 0);
        // weights a^(127-t), t = mt*16 + q*4 + r
        float wb = __expf(cA * (float)(L - 1 - (mt * 16 + q * 4)));
        #pragma unroll
        for (int r = 0; r < 4; ++r) {
            wsum = fmaf(wb, acc[r], wsum);
            if (r < 3) wb *= aInv;
        }
    }
    wsum += __shfl_xor(wsum, 16, 64);
    wsum += __shfl_xor(wsum, 32, 64);

    if (q == 0) {
        agg[(size_t)g * DS + s] = wsum;
        float wgt = __expf(cA * (float)(L * (SEGL - 1 - (g & (SEGL - 1)))));
        atomicAdd(&segAgg[(g >> 4) * DS + s], wsum * wgt);
    }
}

// ---------------------------------------------------------------- K2
// Serial scan over 128 segment aggregates -> segment carries + h_final.
__global__ void ssm_k2(const float* __restrict__ Alog, const float* __restrict__ h0,
                       const float* __restrict__ segAgg, float* __restrict__ segCarry,
                       float* __restrict__ hfin)
{
    const int s = threadIdx.x;                               // 128 threads
    const float aSeg = __expf(Alog[s] * (DTC * L * SEGL));   // a^(L*SEGL)
    float c = h0[s];
    #pragma unroll 8
    for (int sg = 0; sg < NSEG; ++sg) {
        segCarry[sg * DS + s] = c;
        c = fmaf(aSeg, c, segAgg[sg * DS + s]);
    }
    hfin[s] = c;
}

// ---------------------------------------------------------------- K3
// Carry via parallel weighted lookback (independent loads, weights iterated
// largest-last); Bu via MFMA; fp32 scan in LDS; H packed into sHb (overlaid
// on sBu, read-all/barrier/write-all); fused Y = H@C^T + U@D^T via MFMA.
__global__ __launch_bounds__(512, 6) void ssm_k3(
    const float* __restrict__ U, const float* __restrict__ Alog,
    const float* __restrict__ B, const float* __restrict__ C,
    const float* __restrict__ Dm, const float* __restrict__ agg,
    const float* __restrict__ segCarry, float* __restrict__ Y)
{
    __shared__ __align__(16) unsigned short sA[8192];   // 16 KB
    __shared__ __align__(16) float sBu[64 * 130];       // 33.3 KB (H-pack overlays)
    unsigned short* sHb = (unsigned short*)sBu;

    const int g    = blockIdx.x;
    const int tid  = threadIdx.x;
    const int lane = tid & 63;
    const int w    = tid >> 6;
    const int q    = lane >> 4, m = lane & 15;
    const int iC   = 16 * (w & 3) + m;

    stage_U(U + (size_t)g * L * DIN, sA, tid);

    s8v Bf[2], Cf[4], Df[2];
    #pragma unroll
    for (int ks = 0; ks < 2; ++ks)
        Bf[ks] = load_bfrag(B, 16 * w + m, ks * 32 + q * 8, DIN);
    #pragma unroll
    for (int ks = 0; ks < 4; ++ks)
        Cf[ks] = load_bfrag(C, iC, ks * 32 + q * 8, DS);
    #pragma unroll
    for (int ks = 0; ks < 2; ++ks)
        Df[ks] = load_bfrag(Dm, iC, ks * 32 + q * 8, DIN);

    float a_s = 0.f, hreg = 0.f;
    if (tid < DS) {
        const float cA  = Alog[tid] * DTC;
        a_s = __expf(cA);
        const float caL = cA * (float)L;
        const float aL  = __expf(caL);
        const int   j   = g & (SEGL - 1);
        const int   gb  = g & ~(SEGL - 1);
        // carry = segCarry*aL^j + sum_{c<j} aL^(j-1-c)*agg[gb+c]; loads are
        // independent (parallel), weight chain runs smallest->largest.
        float c0 = segCarry[(g >> 4) * DS + tid] * __expf(caL * (float)j);
        float wt = 1.f;
        for (int c = j - 1; c >= 0; --c) {
            c0 = fmaf(wt, agg[(size_t)(gb + c) * DS + tid], c0);
            wt *= aL;
        }
        hreg = c0;
    }
    __syncthreads();

    #pragma unroll
    for (int hh = 0; hh < 2; ++hh) {
        // ---- GEMM1: Bu half-tile (64 t x 128 s)
        #pragma unroll
        for (int mtl = 0; mtl < 4; ++mtl) {
            f4v acc = (f4v){0.f, 0.f, 0.f, 0.f};
            const int mt = hh * 4 + mtl;
            #pragma unroll
            for (int ks = 0; ks < 2; ++ks)
                acc = __builtin_amdgcn_mfma_f32_16x16x32_bf16(*afrag(sA, mt, ks, q, m), Bf[ks], acc, 0, 0, 0);
            #pragma unroll
            for (int r = 0; r < 4; ++r)
                sBu[(mtl * 16 + q * 4 + r) * 130 + 16 * w + m] = acc[r];
        }
        __syncthreads();

        // ---- exact fp32 scan (thread s = column), H in place
        if (tid < DS) {
            #pragma unroll
            for (int r = 0; r < 64; ++r) {
                hreg = fmaf(a_s, hreg, sBu[r * 130 + tid]);
                sBu[r * 130 + tid] = hreg;
            }
        }
        __syncthreads();

        // ---- pack H -> bf16 A-frags; read-all, barrier, write-all (overlay)
        float4 pr[2][2];
        int tt[2], cc[2];
        #pragma unroll
        for (int p = 0; p < 2; ++p) {
            int u  = tid + p * 512;
            int t  = (u & 3) + ((u >> 6) << 2);     // t interleaved: 2-way banks
            int c8 = (u >> 2) & 15;
            tt[p] = t; cc[p] = c8;
            const float4* hp = (const float4*)&sBu[t * 130 + c8 * 8];
            pr[p][0] = hp[0]; pr[p][1] = hp[1];
        }
        __syncthreads();
        #pragma unroll
        for (int p = 0; p < 2; ++p) {
            int t = tt[p], c8 = cc[p];
            int mth = t >> 4, mm = t & 15, ks4 = c8 >> 2, qq = c8 & 3;
            int slot = mth * 256 + ks4 * 64 + qq * 16 + (mm ^ (qq << 2) ^ ks4);
            *(s8v*)&sHb[slot * 8] = pack8(pr[p][0], pr[p][1]);
        }
        __syncthreads();

        // ---- GEMM2: Y half-tile (64 t x 64 i) = H@C^T + U@D^T
        const int mm2 = w >> 2;
        #pragma unroll
        for (int ti = 0; ti < 2; ++ti) {
            const int mtl = mm2 * 2 + ti;
            f4v acc2 = (f4v){0.f, 0.f, 0.f, 0.f};
            #pragma unroll
            for (int ks = 0; ks < 4; ++ks) {
                int slot = mtl * 256 + ks * 64 + q * 16 + (m ^ (q << 2) ^ ks);
                acc2 = __builtin_amdgcn_mfma_f32_16x16x32_bf16(*(const s8v*)&sHb[slot * 8], Cf[ks], acc2, 0, 0, 0);
            }
            #pragma unroll
            for (int ks = 0; ks < 2; ++ks)
                acc2 = __builtin_amdgcn_mfma_f32_16x16x32_bf16(*afrag(sA, hh * 4 + mtl, ks, q, m), Df[ks], acc2, 0, 0, 0);
            const size_t tb = (size_t)g * L + hh * 64 + mtl * 16 + q * 4;
            #pragma unroll
            for (int r = 0; r < 4; ++r)
                Y[(tb + r) * DIN + iC] = acc2[r];
        }
        __syncthreads();   // protect sBu/sHb before next half's GEMM1
    }
}

// ---------------------------------------------------------------- launch
extern "C" void kernel_launch(void* const* d_in, const int* in_sizes, int n_in,
                              void* d_out, int out_size, void* d_ws, size_t ws_size,
                              hipStream_t stream)
{
    const float* U    = (const float*)d_in[0];
    const float* Alog = (const float*)d_in[1];
    const float* B    = (const float*)d_in[2];
    const float* C    = (const float*)d_in[3];
    const float* Dm   = (const float*)d_in[4];
    const float* h0   = (const float*)d_in[5];

    float* out  = (float*)d_out;
    float* Yp   = out;                        // T*DIN
    float* hfin = out + (size_t)TT * DIN;     // 128

    float* agg      = (float*)d_ws;                 // NG*DS    (1 MB)
    float* segAgg   = agg + (size_t)NG * DS;        // NSEG*DS  (64 KB)
    float* segCarry = segAgg + (size_t)NSEG * DS;   // NSEG*DS  (64 KB)

    hipMemsetAsync(segAgg, 0, (size_t)NSEG * DS * sizeof(float), stream);
    ssm_k1<<<NG, 512, 0, stream>>>(U, Alog, B, agg, segAgg);
    ssm_k2<<<1, DS, 0, stream>>>(Alog, h0, segAgg, segCarry, hfin);
    ssm_k3<<<NG, 512, 0, stream>>>(U, Alog, B, C, Dm, agg, segCarry, Yp);
}